// Round 8
// baseline (329.937 us; speedup 1.0000x reference)
//
#include <hip/hip_runtime.h>

// VEConv: E=800000, N=50000, RBF=100, D=64. E % 256 == 0 (3125 blocks of 256).
// Round 8: occupancy attack. Rounds 5/7 both pinned at ~16 waves/CU and
// ~220 us (latency-bound, per-wave wall ~35k cy for a ~2k cy issue stream).
// Packaging change only: 1024-thread blocks (16 waves) share ONE 32 KiB
// weight tile + 16 x 2 KiB sp buffers = 64 KiB LDS -> 2 blocks/CU under both
// LDS (128<=160 KiB) and thread (2048) caps -> 32 waves/CU, double today's
// residency. Per-wave body identical to round 7 (52 VGPR, burst loads,
// 32 MFMA, barrier-free after the one staging barrier).
#define RBF_DIM 100

typedef __attribute__((ext_vector_type(8))) short bf16x8;
typedef __attribute__((ext_vector_type(4))) float f32x4;

// software RNE (prep kernel only)
__device__ __forceinline__ unsigned short f2bf_sw(float f) {
    union { float f; unsigned int u; } v; v.f = f;
    unsigned int r = (v.u + 0x7FFFu + ((v.u >> 16) & 1u)) >> 16;
    return (unsigned short)r;
}

// hardware packed cvt: lo16 = bf16(x), hi16 = bf16(y), RNE
__device__ __forceinline__ unsigned int cvtpk(float x, float y) {
    unsigned int r;
    asm("v_cvt_pk_bf16_f32 %0, %1, %2" : "=v"(r) : "v"(x), "v"(y));
    return r;
}
__device__ __forceinline__ bf16x8 cvt8(f32x4 a, f32x4 b) {
    union { bf16x8 v; unsigned int u[4]; } r;
    r.u[0] = cvtpk(a[0], a[1]);
    r.u[1] = cvtpk(a[2], a[3]);
    r.u[2] = cvtpk(b[0], b[1]);
    r.u[3] = cvtpk(b[2], b[3]);
    return r.v;
}

// ---- pre-kernel: weights as bf16 MFMA fragments, dump order ----
// ws ushort layout: 32 frags x 64 lanes x 8 elems
//   f in [0,16):  W1T frag (t4=f>>2, ks=f&3), k=32ks+8g+j (k=100 -> b1, >100 -> 0)
//   f in [16,24): W2T frag (t4=(f-16)>>1, ks=(f-16)&1)
//   f in [24,32): W3T frag (t4=(f-24)>>1, ks=(f-24)&1)
__global__ void prep_weights(const float* __restrict__ W1, const float* __restrict__ b1,
                             const float* __restrict__ W2, const float* __restrict__ W3,
                             unsigned short* __restrict__ ws) {
    for (int e = threadIdx.x; e < 32 * 64 * 8; e += 256) {
        int f = e >> 9;
        int lane = (e >> 3) & 63;
        int j = e & 7;
        int l15 = lane & 15, g = lane >> 4;
        float v;
        if (f < 16) {
            int t4 = f >> 2, ks = f & 3;
            int k = 32 * ks + 8 * g + j, o = 16 * t4 + l15;
            v = (k < RBF_DIM) ? W1[k * 64 + o] : ((k == RBF_DIM) ? b1[o] : 0.0f);
        } else if (f < 24) {
            int q = f - 16, t4 = q >> 1, ks = q & 1;
            int k = 32 * ks + 8 * g + j, o = 16 * t4 + l15;
            v = W2[k * 64 + o];
        } else {
            int q = f - 24, t4 = q >> 1, ks = q & 1;
            int k = 32 * ks + 8 * g + j, o = 16 * t4 + l15;
            v = W3[k * 64 + o];
        }
        ws[e] = f2bf_sw(v);
    }
}

// ---- main fused kernel: 256 edges/block, 16 waves x 16 edges ----
__global__ __launch_bounds__(1024, 8)
void veconv_main(const float* __restrict__ rbf, const float* __restrict__ edge_f,
                 const float* __restrict__ node,
                 const float* __restrict__ b2, const float* __restrict__ b3,
                 const int* __restrict__ src, const int* __restrict__ dst,
                 const unsigned short* __restrict__ wsw,
                 float* __restrict__ out) {
    __shared__ unsigned short wlds[32 * 512];       // 32 KB fragment-ordered weights
    __shared__ unsigned short sp_lds[16 * 16 * 64]; // 32 KB softplus transpose (per-wave 2KB)

    const int tid = threadIdx.x;
    const int lane = tid & 63, wid = tid >> 6;      // wid in [0,16)
    const int l15 = lane & 15, g = lane >> 4;
    const int ew0 = blockIdx.x * 256 + wid * 16;
    const int eg = ew0 + l15;
    const int swz = (l15 & 7) << 3;

    // ---- burst-issue global loads ----
    const float* rrow = rbf + (long)eg * RBF_DIM;
    const f32x4 ra0 = *(const f32x4*)(rrow + 8 * g);
    const f32x4 ra1 = *(const f32x4*)(rrow + 8 * g + 4);
    const f32x4 rb0 = *(const f32x4*)(rrow + 32 + 8 * g);
    const f32x4 rb1 = *(const f32x4*)(rrow + 32 + 8 * g + 4);
    const f32x4 rc0 = *(const f32x4*)(rrow + 64 + 8 * g);
    const f32x4 rc1 = *(const f32x4*)(rrow + 64 + 8 * g + 4);
    f32x4 rt = (f32x4){0.f, 0.f, 0.f, 0.f};
    if (g == 0) rt = *(const f32x4*)(rrow + 96);
    const float* erow = edge_f + (long)eg * 64;
    const f32x4 ea0 = *(const f32x4*)(erow + 8 * g);
    const f32x4 ea1 = *(const f32x4*)(erow + 8 * g + 4);
    const f32x4 eb0 = *(const f32x4*)(erow + 32 + 8 * g);
    const f32x4 eb1 = *(const f32x4*)(erow + 32 + 8 * g + 4);
    const int4 s4 = *(const int4*)(src + ew0 + 4 * g);
    const int4 d4 = *(const int4*)(dst + ew0 + 4 * g);
    float b2v[4], b3v[4];
#pragma unroll
    for (int t4 = 0; t4 < 4; ++t4) { b2v[t4] = b2[16 * t4 + l15]; b3v[t4] = b3[16 * t4 + l15]; }

    // ---- stage weights to LDS (cooperative, coalesced, 2 uint4/thread) ----
    {
        const uint4* wg = (const uint4*)wsw;
        uint4* wl = (uint4*)wlds;
#pragma unroll
        for (int i = 0; i < 2; ++i) wl[tid + 1024 * i] = wg[tid + 1024 * i];
    }

    // ---- node gathers (depend only on s4) ----
    const int sv[4] = {s4.x, s4.y, s4.z, s4.w};
    const int dv[4] = {d4.x, d4.y, d4.z, d4.w};
    float nd[4][4];
#pragma unroll
    for (int r = 0; r < 4; ++r)
#pragma unroll
        for (int t4 = 0; t4 < 4; ++t4)
            nd[r][t4] = node[(long)sv[r] * 64 + 16 * t4 + l15];

    __syncthreads();   // weights visible to all waves

    const bf16x8* frg = (const bf16x8*)wlds;  // frag f, lane: frg[f*64 + lane]

    // ---- GEMM1: D1[d][e] = W1T @ rbf^T ----
    bf16x8 bfk[4];
    bfk[0] = cvt8(ra0, ra1);
    bfk[1] = cvt8(rb0, rb1);
    bfk[2] = cvt8(rc0, rc1);
    {
        union { bf16x8 v; unsigned int u[4]; } bt;
        bt.u[0] = (g == 0) ? cvtpk(rt[0], rt[1]) : 0u;
        bt.u[1] = (g == 0) ? cvtpk(rt[2], rt[3]) : 0u;
        bt.u[2] = (g == 0) ? 0x3F80u : 0u;   // k=100 bias-1.0 column (lo16)
        bt.u[3] = 0u;
        bfk[3] = bt.v;
    }
    f32x4 acc1[4];
#pragma unroll
    for (int t4 = 0; t4 < 4; ++t4) acc1[t4] = (f32x4){0.f, 0.f, 0.f, 0.f};
#pragma unroll
    for (int ks = 0; ks < 4; ++ks)
#pragma unroll
        for (int t4 = 0; t4 < 4; ++t4)
            acc1[t4] = __builtin_amdgcn_mfma_f32_16x16x32_bf16(frg[(t4 * 4 + ks) * 64 + lane],
                                                               bfk[ks], acc1[t4], 0, 0, 0);

    // ---- softplus(beta=0.5, thr=14) -> sp_lds (own-wave region, no barrier) ----
    // D1 layout: lane (g,l15) holds col e=l15, rows d = 16*t4 + 4*g + r
#pragma unroll
    for (int t4 = 0; t4 < 4; ++t4) {
        float spv[4];
#pragma unroll
        for (int r = 0; r < 4; ++r) {
            float x = acc1[t4][r];
            float bx = 0.5f * x;
            float s = 2.0f * __logf(1.0f + __expf(bx));
            spv[r] = (bx > 14.0f) ? x : s;
        }
        unsigned int p0 = cvtpk(spv[0], spv[1]);
        unsigned int p1 = cvtpk(spv[2], spv[3]);
        int el = (wid * 16 + l15) * 64 + ((16 * t4 + 4 * g) ^ swz);
        *(uint2*)&sp_lds[el] = make_uint2(p0, p1);
    }

    // ---- GEMM2/3 swapped operands: D[e][d] edge-major ----
    bf16x8 aef[2];
    aef[0] = cvt8(ea0, ea1);
    aef[1] = cvt8(eb0, eb1);
    f32x4 acc2[4], acc3[4];
#pragma unroll
    for (int t4 = 0; t4 < 4; ++t4) {
        acc2[t4] = (f32x4){0.f, 0.f, 0.f, 0.f};
        acc3[t4] = (f32x4){0.f, 0.f, 0.f, 0.f};
    }
#pragma unroll
    for (int ks = 0; ks < 2; ++ks) {
        bf16x8 asp = *(const bf16x8*)&sp_lds[(wid * 16 + l15) * 64 + ((32 * ks + 8 * g) ^ swz)];
#pragma unroll
        for (int t4 = 0; t4 < 4; ++t4) {
            acc2[t4] = __builtin_amdgcn_mfma_f32_16x16x32_bf16(asp,
                          frg[(16 + t4 * 2 + ks) * 64 + lane], acc2[t4], 0, 0, 0);
            acc3[t4] = __builtin_amdgcn_mfma_f32_16x16x32_bf16(aef[ks],
                          frg[(24 + t4 * 2 + ks) * 64 + lane], acc3[t4], 0, 0, 0);
        }
    }
    // acc2/acc3: lane (g,l15) holds edge 4g+r, dim 16*t4+l15

    // ---- epilogue: contiguous-dim atomic scatter from accumulators ----
#pragma unroll
    for (int r = 0; r < 4; ++r) {
        float* orow = out + (long)dv[r] * 64 + l15;
#pragma unroll
        for (int t4 = 0; t4 < 4; ++t4) {
            float msg = nd[r][t4] * (acc2[t4][r] + b2v[t4]) + (acc3[t4][r] + b3v[t4]);
            atomicAdd(&orow[16 * t4], msg);
        }
    }
}

extern "C" void kernel_launch(void* const* d_in, const int* in_sizes, int n_in,
                              void* d_out, int out_size, void* d_ws, size_t ws_size,
                              hipStream_t stream) {
    const float* rbf    = (const float*)d_in[0];
    const float* edge_f = (const float*)d_in[1];
    const float* node   = (const float*)d_in[2];
    const float* W1     = (const float*)d_in[3];
    const float* b1     = (const float*)d_in[4];
    const float* W2     = (const float*)d_in[5];
    const float* b2     = (const float*)d_in[6];
    const float* W3     = (const float*)d_in[7];
    const float* b3     = (const float*)d_in[8];
    const int*   src    = (const int*)d_in[9];
    const int*   dst    = (const int*)d_in[10];
    float* out = (float*)d_out;
    unsigned short* ws = (unsigned short*)d_ws;

    const int E = in_sizes[9];              // 800000, divisible by 256

    hipMemsetAsync(d_out, 0, (size_t)out_size * sizeof(float), stream);
    prep_weights<<<1, 256, 0, stream>>>(W1, b1, W2, W3, ws);
    veconv_main<<<E / 256, 1024, 0, stream>>>(rbf, edge_f, node, b2, b3, src, dst, ws, out);
}

// Round 9
// 250.843 us; speedup vs baseline: 1.3153x; 1.3153x over previous
//
#include <hip/hip_runtime.h>

// VEConv: E=800000, N=50000, RBF=100, D=64. E % 128 == 0.
// Round 9: r7 body (best: 224us) + slot-CSR epilogue to remove ALL 51.2M f32
// atomics (r8 showed a throughput wall at ~2.5 TB/s effective with constant
// VALU work; the atomic write-through/coherence traffic is the suspect).
//   build:  hist(dst) -> 2-level exclusive scan -> offs/cursor  (r4-validated)
//   phaseA: r7 GEMM body; epilogue claims CSR slot (1 int atomic/edge) and
//           streams a 128B bf16 msg row per edge (dim-permuted d'=4*l15+t4 so
//           each lane stores one contiguous uint2)
//   phaseB: 1 wave/node sums its contiguous msg rows; out write applies the
//           inverse permutation d = 16*(lane&3)+(lane>>2). No out memset.
// Fallback to the r7 atomic epilogue if ws is too small.
#define RBF_DIM 100

typedef __attribute__((ext_vector_type(8))) short bf16x8;
typedef __attribute__((ext_vector_type(4))) float f32x4;

__device__ __forceinline__ unsigned short f2bf_sw(float f) {
    union { float f; unsigned int u; } v; v.f = f;
    unsigned int r = (v.u + 0x7FFFu + ((v.u >> 16) & 1u)) >> 16;
    return (unsigned short)r;
}
__device__ __forceinline__ float bf2f(unsigned short u) {
    union { unsigned int u; float f; } v; v.u = ((unsigned int)u) << 16;
    return v.f;
}
// hardware packed cvt: lo16 = bf16(x), hi16 = bf16(y), RNE
__device__ __forceinline__ unsigned int cvtpk(float x, float y) {
    unsigned int r;
    asm("v_cvt_pk_bf16_f32 %0, %1, %2" : "=v"(r) : "v"(x), "v"(y));
    return r;
}
__device__ __forceinline__ bf16x8 cvt8(f32x4 a, f32x4 b) {
    union { bf16x8 v; unsigned int u[4]; } r;
    r.u[0] = cvtpk(a[0], a[1]);
    r.u[1] = cvtpk(a[2], a[3]);
    r.u[2] = cvtpk(b[0], b[1]);
    r.u[3] = cvtpk(b[2], b[3]);
    return r.v;
}

// ---- pre-kernel: weights as bf16 MFMA fragments, dump order ----
__global__ void prep_weights(const float* __restrict__ W1, const float* __restrict__ b1,
                             const float* __restrict__ W2, const float* __restrict__ W3,
                             unsigned short* __restrict__ ws) {
    for (int e = threadIdx.x; e < 32 * 64 * 8; e += 256) {
        int f = e >> 9;
        int lane = (e >> 3) & 63;
        int j = e & 7;
        int l15 = lane & 15, g = lane >> 4;
        float v;
        if (f < 16) {
            int t4 = f >> 2, ks = f & 3;
            int k = 32 * ks + 8 * g + j, o = 16 * t4 + l15;
            v = (k < RBF_DIM) ? W1[k * 64 + o] : ((k == RBF_DIM) ? b1[o] : 0.0f);
        } else if (f < 24) {
            int q = f - 16, t4 = q >> 1, ks = q & 1;
            int k = 32 * ks + 8 * g + j, o = 16 * t4 + l15;
            v = W2[k * 64 + o];
        } else {
            int q = f - 24, t4 = q >> 1, ks = q & 1;
            int k = 32 * ks + 8 * g + j, o = 16 * t4 + l15;
            v = W3[k * 64 + o];
        }
        ws[e] = f2bf_sw(v);
    }
}

// ---- CSR build (r4-validated) ----
__global__ void k_hist(const int* __restrict__ dst, int* __restrict__ counts, int E) {
    int i = blockIdx.x * 256 + threadIdx.x;
    if (i < E) atomicAdd(&counts[dst[i]], 1);
}

__global__ void k_bsum(const int* __restrict__ counts, int* __restrict__ bsum, int N) {
    __shared__ int red[4];
    int i = blockIdx.x * 256 + threadIdx.x;
    int v = (i < N) ? counts[i] : 0;
    for (int off = 32; off; off >>= 1) v += __shfl_down(v, off, 64);
    int lane = threadIdx.x & 63, w = threadIdx.x >> 6;
    if (lane == 0) red[w] = v;
    __syncthreads();
    if (threadIdx.x == 0) bsum[blockIdx.x] = red[0] + red[1] + red[2] + red[3];
}

__global__ void k_scan_bsum(int* __restrict__ bsum, int* __restrict__ offs,
                            int NB, int N, int E) {
    __shared__ int s[256];
    int t = threadIdx.x;
    int v = (t < NB) ? bsum[t] : 0;
    s[t] = v;
    __syncthreads();
    for (int off = 1; off < 256; off <<= 1) {
        int x = (t >= off) ? s[t - off] : 0;
        __syncthreads();
        s[t] += x;
        __syncthreads();
    }
    if (t < NB) bsum[t] = s[t] - v;   // exclusive
    if (t == 0) offs[N] = E;
}

__global__ void k_scan_final(const int* __restrict__ counts, const int* __restrict__ bsum,
                             int* __restrict__ offs, int* __restrict__ cursor, int N) {
    __shared__ int s[256];
    int t = threadIdx.x, i = blockIdx.x * 256 + t;
    int v = (i < N) ? counts[i] : 0;
    s[t] = v;
    __syncthreads();
    for (int off = 1; off < 256; off <<= 1) {
        int x = (t >= off) ? s[t - off] : 0;
        __syncthreads();
        s[t] += x;
        __syncthreads();
    }
    if (i < N) {
        int excl = s[t] - v + bsum[blockIdx.x];
        offs[i] = excl;
        cursor[i] = excl;
    }
}

// ---- phase A: 128 edges/block, 8 waves x 16 edges (r7 body) ----
template <bool CSR>
__global__ __launch_bounds__(512, 4)
void veconv_main(const float* __restrict__ rbf, const float* __restrict__ edge_f,
                 const float* __restrict__ node,
                 const float* __restrict__ b2, const float* __restrict__ b3,
                 const int* __restrict__ src, const int* __restrict__ dst,
                 const unsigned short* __restrict__ wsw,
                 float* __restrict__ out,
                 unsigned short* __restrict__ msg, int* __restrict__ cursor) {
    __shared__ unsigned short wlds[32 * 512];      // 32 KB fragment-ordered weights
    __shared__ unsigned short sp_lds[8 * 16 * 64]; // 16 KB softplus transpose (per-wave)

    const int tid = threadIdx.x;
    const int lane = tid & 63, wid = tid >> 6;     // wid in [0,8)
    const int l15 = lane & 15, g = lane >> 4;
    const int ew0 = blockIdx.x * 128 + wid * 16;
    const int eg = ew0 + l15;
    const int swz = (l15 & 7) << 3;

    // ---- burst-issue global loads ----
    const float* rrow = rbf + (long)eg * RBF_DIM;
    const f32x4 ra0 = *(const f32x4*)(rrow + 8 * g);
    const f32x4 ra1 = *(const f32x4*)(rrow + 8 * g + 4);
    const f32x4 rb0 = *(const f32x4*)(rrow + 32 + 8 * g);
    const f32x4 rb1 = *(const f32x4*)(rrow + 32 + 8 * g + 4);
    const f32x4 rc0 = *(const f32x4*)(rrow + 64 + 8 * g);
    const f32x4 rc1 = *(const f32x4*)(rrow + 64 + 8 * g + 4);
    f32x4 rt = (f32x4){0.f, 0.f, 0.f, 0.f};
    if (g == 0) rt = *(const f32x4*)(rrow + 96);
    const float* erow = edge_f + (long)eg * 64;
    const f32x4 ea0 = *(const f32x4*)(erow + 8 * g);
    const f32x4 ea1 = *(const f32x4*)(erow + 8 * g + 4);
    const f32x4 eb0 = *(const f32x4*)(erow + 32 + 8 * g);
    const f32x4 eb1 = *(const f32x4*)(erow + 32 + 8 * g + 4);
    const int4 s4 = *(const int4*)(src + ew0 + 4 * g);
    const int4 d4 = *(const int4*)(dst + ew0 + 4 * g);
    float b2v[4], b3v[4];
#pragma unroll
    for (int t4 = 0; t4 < 4; ++t4) { b2v[t4] = b2[16 * t4 + l15]; b3v[t4] = b3[16 * t4 + l15]; }

    // ---- stage weights to LDS (cooperative, coalesced, 4 uint4/thread) ----
    {
        const uint4* wg = (const uint4*)wsw;
        uint4* wl = (uint4*)wlds;
#pragma unroll
        for (int i = 0; i < 4; ++i) wl[tid + 512 * i] = wg[tid + 512 * i];
    }

    // ---- node gathers (depend only on s4) ----
    const int sv[4] = {s4.x, s4.y, s4.z, s4.w};
    const int dv[4] = {d4.x, d4.y, d4.z, d4.w};
    float nd[4][4];
#pragma unroll
    for (int r = 0; r < 4; ++r)
#pragma unroll
        for (int t4 = 0; t4 < 4; ++t4)
            nd[r][t4] = node[(long)sv[r] * 64 + 16 * t4 + l15];

    __syncthreads();   // weights visible to all waves

    const bf16x8* frg = (const bf16x8*)wlds;

    // ---- GEMM1: D1[d][e] = W1T @ rbf^T ----
    bf16x8 bfk[4];
    bfk[0] = cvt8(ra0, ra1);
    bfk[1] = cvt8(rb0, rb1);
    bfk[2] = cvt8(rc0, rc1);
    {
        union { bf16x8 v; unsigned int u[4]; } bt;
        bt.u[0] = (g == 0) ? cvtpk(rt[0], rt[1]) : 0u;
        bt.u[1] = (g == 0) ? cvtpk(rt[2], rt[3]) : 0u;
        bt.u[2] = (g == 0) ? 0x3F80u : 0u;   // k=100 bias-1.0 column (lo16)
        bt.u[3] = 0u;
        bfk[3] = bt.v;
    }
    f32x4 acc1[4];
#pragma unroll
    for (int t4 = 0; t4 < 4; ++t4) acc1[t4] = (f32x4){0.f, 0.f, 0.f, 0.f};
#pragma unroll
    for (int ks = 0; ks < 4; ++ks)
#pragma unroll
        for (int t4 = 0; t4 < 4; ++t4)
            acc1[t4] = __builtin_amdgcn_mfma_f32_16x16x32_bf16(frg[(t4 * 4 + ks) * 64 + lane],
                                                               bfk[ks], acc1[t4], 0, 0, 0);

    // ---- softplus(beta=0.5, thr=14) -> sp_lds (own-wave region, no barrier) ----
#pragma unroll
    for (int t4 = 0; t4 < 4; ++t4) {
        float spv[4];
#pragma unroll
        for (int r = 0; r < 4; ++r) {
            float x = acc1[t4][r];
            float bx = 0.5f * x;
            float s = 2.0f * __logf(1.0f + __expf(bx));
            spv[r] = (bx > 14.0f) ? x : s;
        }
        unsigned int p0 = cvtpk(spv[0], spv[1]);
        unsigned int p1 = cvtpk(spv[2], spv[3]);
        int el = (wid * 16 + l15) * 64 + ((16 * t4 + 4 * g) ^ swz);
        *(uint2*)&sp_lds[el] = make_uint2(p0, p1);
    }

    // ---- GEMM2/3 swapped operands: D[e][d] edge-major ----
    bf16x8 aef[2];
    aef[0] = cvt8(ea0, ea1);
    aef[1] = cvt8(eb0, eb1);
    f32x4 acc2[4], acc3[4];
#pragma unroll
    for (int t4 = 0; t4 < 4; ++t4) {
        acc2[t4] = (f32x4){0.f, 0.f, 0.f, 0.f};
        acc3[t4] = (f32x4){0.f, 0.f, 0.f, 0.f};
    }
#pragma unroll
    for (int ks = 0; ks < 2; ++ks) {
        bf16x8 asp = *(const bf16x8*)&sp_lds[(wid * 16 + l15) * 64 + ((32 * ks + 8 * g) ^ swz)];
#pragma unroll
        for (int t4 = 0; t4 < 4; ++t4) {
            acc2[t4] = __builtin_amdgcn_mfma_f32_16x16x32_bf16(asp,
                          frg[(16 + t4 * 2 + ks) * 64 + lane], acc2[t4], 0, 0, 0);
            acc3[t4] = __builtin_amdgcn_mfma_f32_16x16x32_bf16(aef[ks],
                          frg[(24 + t4 * 2 + ks) * 64 + lane], acc3[t4], 0, 0, 0);
        }
    }
    // acc2/acc3: lane (g,l15) holds edge 4g+r, dim 16*t4+l15

    if constexpr (CSR) {
        // ---- claim slots (1 int atomic per edge, on l15==0), broadcast in-group ----
        int slot[4];
#pragma unroll
        for (int r = 0; r < 4; ++r) {
            int sl = 0;
            if (l15 == 0) sl = atomicAdd(&cursor[dv[r]], 1);
            slot[r] = __shfl(sl, lane & 48, 64);
        }
        // ---- stream msg rows: dim-permuted d' = 4*l15 + t4, 8B/lane contiguous ----
#pragma unroll
        for (int r = 0; r < 4; ++r) {
            float m0 = nd[r][0] * (acc2[0][r] + b2v[0]) + (acc3[0][r] + b3v[0]);
            float m1 = nd[r][1] * (acc2[1][r] + b2v[1]) + (acc3[1][r] + b3v[1]);
            float m2 = nd[r][2] * (acc2[2][r] + b2v[2]) + (acc3[2][r] + b3v[2]);
            float m3 = nd[r][3] * (acc2[3][r] + b2v[3]) + (acc3[3][r] + b3v[3]);
            *(uint2*)(msg + (long)slot[r] * 64 + 4 * l15) =
                make_uint2(cvtpk(m0, m1), cvtpk(m2, m3));
        }
    } else {
        // fallback: contiguous-dim f32 atomic scatter
#pragma unroll
        for (int r = 0; r < 4; ++r) {
            float* orow = out + (long)dv[r] * 64 + l15;
#pragma unroll
            for (int t4 = 0; t4 < 4; ++t4) {
                float m = nd[r][t4] * (acc2[t4][r] + b2v[t4]) + (acc3[t4][r] + b3v[t4]);
                atomicAdd(&orow[16 * t4], m);
            }
        }
    }
}

// ---- phase B: 1 wave per node; msg rows contiguous; inverse dim permutation ----
__global__ __launch_bounds__(256)
void k_segsum(const unsigned short* __restrict__ msg, const int* __restrict__ offs,
              float* __restrict__ out, int N) {
    int wid = threadIdx.x >> 6, lane = threadIdx.x & 63;
    int n = blockIdx.x * 4 + wid;
    if (n >= N) return;
    int beg = offs[n], end = offs[n + 1];
    float s0 = 0.f, s1 = 0.f, s2 = 0.f, s3 = 0.f;
    int i = beg;
    for (; i + 4 <= end; i += 4) {
        s0 += bf2f(msg[(long)(i + 0) * 64 + lane]);
        s1 += bf2f(msg[(long)(i + 1) * 64 + lane]);
        s2 += bf2f(msg[(long)(i + 2) * 64 + lane]);
        s3 += bf2f(msg[(long)(i + 3) * 64 + lane]);
    }
    for (; i < end; ++i) s0 += bf2f(msg[(long)i * 64 + lane]);
    // lane holds d' = lane = 4*l15' + t4'  ->  d = 16*t4' + l15'
    out[(long)n * 64 + 16 * (lane & 3) + (lane >> 2)] = s0 + s1 + s2 + s3;
}

extern "C" void kernel_launch(void* const* d_in, const int* in_sizes, int n_in,
                              void* d_out, int out_size, void* d_ws, size_t ws_size,
                              hipStream_t stream) {
    const float* rbf    = (const float*)d_in[0];
    const float* edge_f = (const float*)d_in[1];
    const float* node   = (const float*)d_in[2];
    const float* W1     = (const float*)d_in[3];
    const float* b1     = (const float*)d_in[4];
    const float* W2     = (const float*)d_in[5];
    const float* b2     = (const float*)d_in[6];
    const float* W3     = (const float*)d_in[7];
    const float* b3     = (const float*)d_in[8];
    const int*   src    = (const int*)d_in[9];
    const int*   dst    = (const int*)d_in[10];
    float* out = (float*)d_out;
    char* ws = (char*)d_ws;

    const int E = in_sizes[9];               // 800000 (divisible by 128)
    const int N = in_sizes[2] / 64;          // 50000
    const int NB = (N + 255) / 256;          // 196 scan blocks

    // ws layout
    size_t off = 32768;                      // weights: 16384 ushort
    size_t counts_off = off; off += (size_t)N * 4;
    size_t cursor_off = off; off += (size_t)N * 4;
    size_t offs_off   = off; off += ((size_t)N + 1) * 4;
    off = (off + 255) & ~(size_t)255;
    size_t bsum_off = off; off += (size_t)NB * 4;
    off = (off + 255) & ~(size_t)255;
    size_t msg_off = off; off += (size_t)E * 64 * 2;
    const bool use_csr = (NB <= 256) && (ws_size >= off);

    unsigned short* wsw = (unsigned short*)(ws);
    int* counts         = (int*)(ws + counts_off);
    int* cursor         = (int*)(ws + cursor_off);
    int* offs           = (int*)(ws + offs_off);
    int* bsum           = (int*)(ws + bsum_off);
    unsigned short* msg = (unsigned short*)(ws + msg_off);

    prep_weights<<<1, 256, 0, stream>>>(W1, b1, W2, W3, wsw);

    if (use_csr) {
        hipMemsetAsync(counts, 0, (size_t)N * 4, stream);
        k_hist<<<(E + 255) / 256, 256, 0, stream>>>(dst, counts, E);
        k_bsum<<<NB, 256, 0, stream>>>(counts, bsum, N);
        k_scan_bsum<<<1, 256, 0, stream>>>(bsum, offs, NB, N, E);
        k_scan_final<<<NB, 256, 0, stream>>>(counts, bsum, offs, cursor, N);
        veconv_main<true><<<E / 128, 512, 0, stream>>>(rbf, edge_f, node, b2, b3, src, dst,
                                                       wsw, out, msg, cursor);
        k_segsum<<<(N + 3) / 4, 256, 0, stream>>>(msg, offs, out, N);
    } else {
        hipMemsetAsync(out, 0, (size_t)out_size * sizeof(float), stream);
        veconv_main<false><<<E / 128, 512, 0, stream>>>(rbf, edge_f, node, b2, b3, src, dst,
                                                        wsw, out, msg, cursor);
    }
}